// Round 9
// baseline (385.366 us; speedup 1.0000x reference)
//
#include <hip/hip_runtime.h>

#define HDIM 2048
#define HH (HDIM * HDIM)          // 4,194,304
#define NIDX 2000000
#define BINS 256
#define NCOPY 16
#define TL_BLOCKS 2048
#define NCHUNK 2000               // sort chunks: 1000 samples each (250 int4)
#define CH_I4 250
#define NWIN 64                   // window = pd>>16 (64K pixels, 256KB packed)

// workspace layout (bytes) — ends 50,331,648 (< R8's proven 54.7 MB)
#define PART_OFF     0                      // double partials[2048] = 16 KB
#define TAB_OFF      16384                  // float tab[3*BINS]
#define WGL_OFF      20480                  // uint W_d[65] + W_r[65]
#define HIST_OFF     24576                  // uint hist[16][6][256] = 96 KB
#define CNT_D_OFF    131072                 // ushort cnt_d[2000][64] = 256 KB
#define CNT_R_OFF    393216
#define OFF_D_OFF    655360                 // uint off_d[2000][64] = 512 KB
#define OFF_R_OFF    1179648
#define FLAGS_OFF    2097152                // uchar flags[HH] = 4 MB
#define SORT_D_OFF   6291456                // ushort sorted_d[NIDX] = 4 MB
#define SORT_R_OFF   10485760               // ushort sorted_r[NIDX] = 4 MB
#define PACKED_D_OFF 16777216               // uint packed_d[HH] = 16 MB
#define PACKED_R_OFF 33554432               // uint packed_r[HH] = 16 MB

// Node 1: zero hist/flags + per-chunk window COUNTS (block-owned, LDS only —
// no global atomics, R6 lesson) + pack 3 channel bins into one uint/pixel.
__global__ __launch_bounds__(256) void pack_kernel(
    const float* __restrict__ ref, const float* __restrict__ tgt,
    const float* __restrict__ msrc, const float* __restrict__ mtar,
    const int* __restrict__ i0, const int* __restrict__ i1,
    const int* __restrict__ i2, const int* __restrict__ i3,
    unsigned* __restrict__ packed_d, unsigned* __restrict__ packed_r,
    unsigned* __restrict__ hist, unsigned* __restrict__ flags32,
    unsigned short* __restrict__ cnt_d, unsigned short* __restrict__ cnt_r)
{
    __shared__ unsigned cntd[NWIN], cntr[NWIN];
    const int t = threadIdx.x;
    const int gtid = blockIdx.x * 256 + t;
    const int stride = gridDim.x * 256;

    for (int k = gtid; k < NCOPY * 6 * BINS; k += stride) hist[k] = 0;
    for (int k = gtid; k < HH / 4; k += stride) flags32[k] = 0;

    // ---- per-chunk window counting (chunks 0..1999, block-owned) ----
    if (blockIdx.x < NCHUNK) {
        if (t < NWIN) { cntd[t] = 0; cntr[t] = 0; }
        __syncthreads();
        if (t < CH_I4) {
            const int q = blockIdx.x * CH_I4 + t;
            const int4 a = ((const int4*)i0)[q];
            const int4 b = ((const int4*)i1)[q];
            const int4 c = ((const int4*)i2)[q];
            const int4 d = ((const int4*)i3)[q];
            const int pd[4] = {a.x * HDIM + b.x, a.y * HDIM + b.y, a.z * HDIM + b.z, a.w * HDIM + b.w};
            const int pr[4] = {c.x * HDIM + d.x, c.y * HDIM + d.y, c.z * HDIM + d.z, c.w * HDIM + d.w};
#pragma unroll
            for (int k = 0; k < 4; k++) atomicAdd(&cntd[pd[k] >> 16], 1u);
#pragma unroll
            for (int k = 0; k < 4; k++) atomicAdd(&cntr[pr[k] >> 16], 1u);
        }
        __syncthreads();
        if (t < NWIN) {
            cnt_d[blockIdx.x * NWIN + t] = (unsigned short)cntd[t];
            cnt_r[blockIdx.x * NWIN + t] = (unsigned short)cntr[t];
        }
    }

    // ---- image pack (validated math; mask folded: v*0 -> bin 0) ----
    for (int g = gtid; g < HH / 4; g += stride) {
        const int p = g * 4;
        const float4 ms4 = *(const float4*)(msrc + p);
        const float4 mt4 = *(const float4*)(mtar + p);
        const float ms[4] = {ms4.x, ms4.y, ms4.z, ms4.w};
        const float mt[4] = {mt4.x, mt4.y, mt4.z, mt4.w};
        unsigned od[4] = {0, 0, 0, 0}, orr[4] = {0, 0, 0, 0};
#pragma unroll
        for (int c = 0; c < 3; c++) {
            const float4 rv = *(const float4*)(ref + c * HH + p);
            const float4 tv = *(const float4*)(tgt + c * HH + p);
            const float r[4] = {rv.x, rv.y, rv.z, rv.w};
            const float tt[4] = {tv.x, tv.y, tv.z, tv.w};
#pragma unroll
            for (int k = 0; k < 4; k++) {
                const float vd = ((r[k] + 1.0f) * 0.5f) * 255.0f * ms[k];
                const float vr = ((tt[k] + 1.0f) * 0.5f) * 255.0f * mt[k];
                const unsigned bd = (unsigned)(int)fminf(fmaxf(floorf(vd), 0.0f), 255.0f);
                const unsigned br = (unsigned)(int)fminf(fmaxf(floorf(vr), 0.0f), 255.0f);
                od[k]  |= bd << (8 * c);
                orr[k] |= br << (8 * c);
            }
        }
        *(uint4*)(packed_d + p) = make_uint4(od[0], od[1], od[2], od[3]);
        *(uint4*)(packed_r + p) = make_uint4(orr[0], orr[1], orr[2], orr[3]);
    }
}

// Node 2: exact global offsets from counts (1 block; deterministic integer
// prefix sums; capacity-exact so no overflow handling needed anywhere).
__global__ __launch_bounds__(1024) void off_kernel(
    const unsigned short* __restrict__ cnt_d, const unsigned short* __restrict__ cnt_r,
    unsigned* __restrict__ off_d, unsigned* __restrict__ off_r, unsigned* __restrict__ Wg)
{
    __shared__ unsigned psum[16][NWIN];
    __shared__ unsigned segbase[16][NWIN];
    __shared__ unsigned Wl[NWIN + 1];
    const int t = threadIdx.x;
    const int w = t & 63, seg = t >> 6;          // 16 segments x 125 chunks

    for (int side = 0; side < 2; side++) {
        const unsigned short* cnt = side ? cnt_r : cnt_d;
        unsigned* off = side ? off_r : off_d;
        unsigned s = 0;
        for (int b = seg * 125; b < seg * 125 + 125; b++) s += cnt[b * NWIN + w];
        psum[seg][w] = s;
        __syncthreads();
        if (t < NWIN) {
            unsigned run = 0;
            for (int sg = 0; sg < 16; sg++) { segbase[sg][t] = run; run += psum[sg][t]; }
            unsigned inc = run;                   // inclusive scan over w (wave64)
            for (int d = 1; d < 64; d <<= 1) {
                const unsigned y = __shfl_up(inc, d, 64);
                if (t >= d) inc += y;
            }
            Wl[t] = inc - run;                    // exclusive
            if (t == 63) Wl[64] = inc;            // total = NIDX
        }
        __syncthreads();
        unsigned run = Wl[w] + segbase[seg][w];
        for (int b = seg * 125; b < seg * 125 + 125; b++) {
            off[b * NWIN + w] = run;
            run += cnt[b * NWIN + w];
        }
        if (t < NWIN + 1) Wg[side * (NWIN + 1) + t] = Wl[t];
        __syncthreads();
    }
}

// Node 3: place each sample into its exact sorted slot (LDS cursors only —
// every slot written exactly once; within-cell order benign for the
// order-independent histogram/flags).
__global__ __launch_bounds__(256) void place_kernel(
    const int* __restrict__ i0, const int* __restrict__ i1,
    const int* __restrict__ i2, const int* __restrict__ i3,
    const unsigned* __restrict__ off_d, const unsigned* __restrict__ off_r,
    unsigned short* __restrict__ sorted_d, unsigned short* __restrict__ sorted_r)
{
    __shared__ unsigned cur[NWIN];
    const int b = blockIdx.x;
    const int t = threadIdx.x;

    if (t < NWIN) cur[t] = off_d[b * NWIN + t];
    __syncthreads();
    if (t < CH_I4) {
        const int q = b * CH_I4 + t;
        const int4 a = ((const int4*)i0)[q];
        const int4 bb = ((const int4*)i1)[q];
        const int pd[4] = {a.x * HDIM + bb.x, a.y * HDIM + bb.y, a.z * HDIM + bb.z, a.w * HDIM + bb.w};
#pragma unroll
        for (int k = 0; k < 4; k++) {
            const unsigned pos = atomicAdd(&cur[pd[k] >> 16], 1u);
            sorted_d[pos] = (unsigned short)(pd[k] & 0xFFFF);
        }
    }
    __syncthreads();
    if (t < NWIN) cur[t] = off_r[b * NWIN + t];
    __syncthreads();
    if (t < CH_I4) {
        const int q = b * CH_I4 + t;
        const int4 c = ((const int4*)i2)[q];
        const int4 d = ((const int4*)i3)[q];
        const int pr[4] = {c.x * HDIM + d.x, c.y * HDIM + d.y, c.z * HDIM + d.z, c.w * HDIM + d.w};
#pragma unroll
        for (int k = 0; k < 4; k++) {
            const unsigned pos = atomicAdd(&cur[pr[k] >> 16], 1u);
            sorted_r[pos] = (unsigned short)(pr[k] & 0xFFFF);
        }
    }
}

// Node 4: SORTED gather histogram. Consecutive entries = consecutive pixel
// addresses -> wave-level gathers coalesce into whole lines (each packed
// line fetched ~once, vs 2.8 TB/s random-line ceiling of R3/R5). Window
// reconstructed from global starts W (position-based, LDS bsearch+advance).
// Bin-0 in registers; flags idempotent bytes; 16-copy burst flush.
__global__ __launch_bounds__(256) void whist_kernel(
    const unsigned* __restrict__ packed_d, const unsigned* __restrict__ packed_r,
    const unsigned short* __restrict__ sorted_d, const unsigned short* __restrict__ sorted_r,
    const unsigned* __restrict__ Wg,
    unsigned char* __restrict__ flags, unsigned* __restrict__ hist)
{
    __shared__ unsigned lhist[6 * BINS];
    __shared__ unsigned Ws[NWIN + 1];
    const int t = threadIdx.x;
    for (int k = t; k < 6 * BINS; k += 256) lhist[k] = 0;
    if (t < NWIN + 1) Ws[t] = Wg[t];
    __syncthreads();

    unsigned z0 = 0, z1 = 0, z2 = 0, z3 = 0, z4 = 0, z5 = 0;
    const int stride = gridDim.x * 256;

    // ---- d side: bins 0..2 + flags ----
    for (int q = blockIdx.x * 256 + t; q < NIDX / 4; q += stride) {
        const uint2 sv = ((const uint2*)sorted_d)[q];
        const unsigned lo[4] = {sv.x & 0xFFFFu, sv.x >> 16, sv.y & 0xFFFFu, sv.y >> 16};
        const unsigned e0 = (unsigned)q * 4u;
        int wlo = 0, whi = NWIN;
        while (wlo + 1 < whi) { const int mid = (wlo + whi) >> 1; if (Ws[mid] <= e0) wlo = mid; else whi = mid; }
        int w = wlo;
#pragma unroll
        for (int k = 0; k < 4; k++) {
            const unsigned e = e0 + k;
            while (w < NWIN - 1 && Ws[w + 1] <= e) w++;
            const int pd = (w << 16) | (int)lo[k];
            const unsigned wd = packed_d[pd];
            flags[pd] = 1;
            const unsigned d0 =  wd        & 255u;
            const unsigned d1 = (wd >> 8 ) & 255u;
            const unsigned d2 = (wd >> 16) & 255u;
            if (d0) atomicAdd(&lhist[           d0], 1u); else z0++;
            if (d1) atomicAdd(&lhist[1 * BINS + d1], 1u); else z1++;
            if (d2) atomicAdd(&lhist[2 * BINS + d2], 1u); else z2++;
        }
    }
    __syncthreads();
    if (t < NWIN + 1) Ws[t] = Wg[NWIN + 1 + t];
    __syncthreads();
    // ---- r side: bins 3..5 ----
    for (int q = blockIdx.x * 256 + t; q < NIDX / 4; q += stride) {
        const uint2 sv = ((const uint2*)sorted_r)[q];
        const unsigned lo[4] = {sv.x & 0xFFFFu, sv.x >> 16, sv.y & 0xFFFFu, sv.y >> 16};
        const unsigned e0 = (unsigned)q * 4u;
        int wlo = 0, whi = NWIN;
        while (wlo + 1 < whi) { const int mid = (wlo + whi) >> 1; if (Ws[mid] <= e0) wlo = mid; else whi = mid; }
        int w = wlo;
#pragma unroll
        for (int k = 0; k < 4; k++) {
            const unsigned e = e0 + k;
            while (w < NWIN - 1 && Ws[w + 1] <= e) w++;
            const int pr = (w << 16) | (int)lo[k];
            const unsigned wr = packed_r[pr];
            const unsigned r0 =  wr        & 255u;
            const unsigned r1 = (wr >> 8 ) & 255u;
            const unsigned r2 = (wr >> 16) & 255u;
            if (r0) atomicAdd(&lhist[3 * BINS + r0], 1u); else z3++;
            if (r1) atomicAdd(&lhist[4 * BINS + r1], 1u); else z4++;
            if (r2) atomicAdd(&lhist[5 * BINS + r2], 1u); else z5++;
        }
    }

    if (z0) atomicAdd(&lhist[0 * BINS], z0);
    if (z1) atomicAdd(&lhist[1 * BINS], z1);
    if (z2) atomicAdd(&lhist[2 * BINS], z2);
    if (z3) atomicAdd(&lhist[3 * BINS], z3);
    if (z4) atomicAdd(&lhist[4 * BINS], z4);
    if (z5) atomicAdd(&lhist[5 * BINS], z5);
    __syncthreads();
    unsigned* h = hist + (blockIdx.x & (NCOPY - 1)) * (6 * BINS);
    for (int k = t; k < 6 * BINS; k += 256) {
        const unsigned v = lhist[k];
        if (v) atomicAdd(&h[k], v);
    }
}

// Node 5: transfer table (1 block). Validated logic unchanged.
__global__ __launch_bounds__(256) void table_kernel(
    const unsigned* __restrict__ hist, float* __restrict__ tabg)
{
    __shared__ float    cdf[6 * BINS];
    __shared__ unsigned wsum[4];

    const int t    = threadIdx.x;
    const int lane = t & 63;
    const int wid  = t >> 6;

    for (int ch = 0; ch < 6; ch++) {
        unsigned x = 0;
#pragma unroll
        for (int cp = 0; cp < NCOPY; cp++) x += hist[cp * (6 * BINS) + ch * BINS + t];
#pragma unroll
        for (int d = 1; d < 64; d <<= 1) {
            const unsigned y = __shfl_up(x, d, 64);
            if (lane >= d) x += y;
        }
        if (lane == 63) wsum[wid] = x;
        __syncthreads();
        unsigned prefix = 0;
        for (int w = 0; w < wid; w++) prefix += wsum[w];
        x += prefix;
        cdf[ch * BINS + t] = (float)x / 2000000.0f;
        __syncthreads();
    }
    for (int c = 0; c < 3; c++) {
        float o;
        if (t == 0)             o = 0.0f;
        else if (t == BINS - 1) o = 255.0f;
        else {
            const float v = cdf[c * BINS + t];
            const float* arr = cdf + (3 + c) * BINS;
            int lo = 0, hi = 256;
            while (lo < hi) { const int mid = (lo + hi) >> 1; if (arr[mid] < v) lo = mid + 1; else hi = mid; }
            const int J0 = ((lo > 1) ? lo : 1) - 1;
            int lo2 = 0, hi2 = 256;
            while (lo2 < hi2) { const int mid = (lo2 + hi2) >> 1; if (arr[mid] <= v) lo2 = mid + 1; else hi2 = mid; }
            const int J1 = ((lo2 - 1) < 254 ? (lo2 - 1) : 254);
            const bool found = (lo2 >= 1) && (J0 <= J1);
            o = found ? (float)(J0 + 1) : (float)t;
        }
        tabg[c * BINS + t] = o;
    }
}

// Node 6: streaming loss (unchanged validated logic; flags byte array).
__global__ __launch_bounds__(256) void tabloss_kernel(
    const float* __restrict__ inp, const float* __restrict__ ref,
    const float* __restrict__ msrc, const float* __restrict__ tabg,
    const unsigned char* __restrict__ flags, double* __restrict__ partials)
{
    __shared__ float  tab[3 * BINS];
    __shared__ double red[256];

    const int t = threadIdx.x;
    for (int k = t; k < 3 * BINS; k += 256) tab[k] = tabg[k];
    __syncthreads();

    double local = 0.0;
    const int stride = gridDim.x * 256;
    for (int g = blockIdx.x * 256 + t; g < HH / 4; g += stride) {
        const int p = g * 4;
        const float4 mv = *(const float4*)(msrc + p);
        const uchar4 fw = *(const uchar4*)(flags + p);
        const unsigned samp[4] = {fw.x, fw.y, fw.z, fw.w};
        const float m[4] = {mv.x, mv.y, mv.z, mv.w};
#pragma unroll
        for (int c = 0; c < 3; c++) {
            const float4 rv = *(const float4*)(ref + c * HH + p);
            const float4 iv = *(const float4*)(inp + c * HH + p);
            const float r[4] = {rv.x, rv.y, rv.z, rv.w};
            const float x4[4] = {iv.x, iv.y, iv.z, iv.w};
            float s = 0.0f;
#pragma unroll
            for (int k = 0; k < 4; k++) {
                const float mm = m[k];
                const float refm = ((r[k] + 1.0f) * 0.5f) * 255.0f * mm;
                const float inpm = ((x4[k] + 1.0f) * 0.5f) * 255.0f * mm;
                float matchv;
                if (samp[k]) {
                    const int bidx = (int)fminf(fmaxf(refm, 0.0f), 255.0f);
                    matchv = tab[c * BINS + bidx];
                } else {
                    matchv = refm;
                }
                const float dd = inpm - matchv * mm;
                s += dd * dd;
            }
            local += (double)s;
        }
    }
    red[t] = local;
    __syncthreads();
    for (int s2 = 128; s2 > 0; s2 >>= 1) {
        if (t < s2) red[t] += red[t + s2];
        __syncthreads();
    }
    if (t == 0) partials[blockIdx.x] = red[0];
}

// Node 7: single-block finalize.
__global__ __launch_bounds__(256) void finalize_kernel(
    const double* __restrict__ partials, float* __restrict__ out)
{
    const int t = threadIdx.x;
    double s = 0.0;
    for (int k = t; k < TL_BLOCKS; k += 256) s += partials[k];
    __shared__ double red[256];
    red[t] = s;
    __syncthreads();
    for (int s2 = 128; s2 > 0; s2 >>= 1) {
        if (t < s2) red[t] += red[t + s2];
        __syncthreads();
    }
    if (t == 0) out[0] = (float)(red[0] / (double)(3 * HH));
}

extern "C" void kernel_launch(void* const* d_in, const int* in_sizes, int n_in,
                              void* d_out, int out_size, void* d_ws, size_t ws_size,
                              hipStream_t stream)
{
    const float* input_data  = (const float*)d_in[0];
    const float* target_data = (const float*)d_in[1];
    const float* mask_src    = (const float*)d_in[2];
    const float* mask_tar    = (const float*)d_in[3];
    const int*   i0          = (const int*)d_in[4];
    const int*   i1          = (const int*)d_in[5];
    const int*   i2          = (const int*)d_in[6];
    const int*   i3          = (const int*)d_in[7];
    const float* ref_data    = (const float*)d_in[8];
    float* out = (float*)d_out;

    char* ws = (char*)d_ws;
    double*         partials = (double*)(ws + PART_OFF);
    float*          tabg     = (float*)(ws + TAB_OFF);
    unsigned*       Wg       = (unsigned*)(ws + WGL_OFF);
    unsigned*       hist     = (unsigned*)(ws + HIST_OFF);
    unsigned short* cnt_d    = (unsigned short*)(ws + CNT_D_OFF);
    unsigned short* cnt_r    = (unsigned short*)(ws + CNT_R_OFF);
    unsigned*       off_d    = (unsigned*)(ws + OFF_D_OFF);
    unsigned*       off_r    = (unsigned*)(ws + OFF_R_OFF);
    unsigned*       flags32  = (unsigned*)(ws + FLAGS_OFF);
    unsigned char*  flags    = (unsigned char*)(ws + FLAGS_OFF);
    unsigned short* sorted_d = (unsigned short*)(ws + SORT_D_OFF);
    unsigned short* sorted_r = (unsigned short*)(ws + SORT_R_OFF);
    unsigned*       packed_d = (unsigned*)(ws + PACKED_D_OFF);
    unsigned*       packed_r = (unsigned*)(ws + PACKED_R_OFF);

    pack_kernel<<<2048, 256, 0, stream>>>(ref_data, target_data, mask_src, mask_tar,
                                          i0, i1, i2, i3,
                                          packed_d, packed_r, hist, flags32, cnt_d, cnt_r);
    off_kernel<<<1, 1024, 0, stream>>>(cnt_d, cnt_r, off_d, off_r, Wg);
    place_kernel<<<NCHUNK, 256, 0, stream>>>(i0, i1, i2, i3, off_d, off_r, sorted_d, sorted_r);
    whist_kernel<<<2048, 256, 0, stream>>>(packed_d, packed_r, sorted_d, sorted_r, Wg,
                                           flags, hist);
    table_kernel<<<1, 256, 0, stream>>>(hist, tabg);
    tabloss_kernel<<<TL_BLOCKS, 256, 0, stream>>>(input_data, ref_data, mask_src, tabg,
                                                  flags, partials);
    finalize_kernel<<<1, 256, 0, stream>>>(partials, out);
}